// Round 6
// baseline (210.567 us; speedup 1.0000x reference)
//
#include <hip/hip_runtime.h>
#include <hip/hip_bf16.h>
#include <cstddef>

#define BATCH 4
#define CCH 256
#define NHEAD 8
#define DHEAD 32
#define NZ 1024
#define NX 4096
#define NTOK 5120
#define LKV 1280
#define QC 0.25503486f   // SCALE * log2(e), folded into q

typedef __attribute__((ext_vector_type(8))) short bf16x8;
typedef __attribute__((ext_vector_type(4))) float floatx4;

__device__ inline short f2bf(float f) {
  __hip_bfloat16 h = __float2bfloat16(f);
  return __builtin_bit_cast(short, h);
}
__device__ inline unsigned int pk2(float a, float b) {   // RNE
  unsigned int lo = (unsigned short)f2bf(a);
  unsigned int hi = (unsigned short)f2bf(b);
  return lo | (hi << 16);
}
// fast pack: round-half-up + byte-perm (hot path; a,b > 0)
__device__ inline unsigned int pk2f(float a, float b) {
  unsigned int ua = __builtin_bit_cast(unsigned int, a) + 0x8000u;
  unsigned int ub = __builtin_bit_cast(unsigned int, b) + 0x8000u;
  return __builtin_amdgcn_perm(ub, ua, 0x07060302u);
}
__device__ inline void cvt8(const float* __restrict__ src, short* __restrict__ dst, int i) {
  float4 v0 = ((const float4*)src)[i * 2];
  float4 v1 = ((const float4*)src)[i * 2 + 1];
  uint4 u;
  u.x = pk2(v0.x, v0.y); u.y = pk2(v0.z, v0.w);
  u.z = pk2(v1.x, v1.y); u.w = pk2(v1.z, v1.w);
  ((uint4*)dst)[i] = u;
}

// ---------------- prep: weight converts + Wsr reorder + x->bf16, one launch
// blocks [0,32): Wq -> Wqb ; [32,96): Wkv -> Wkvb ; [96,128): Wproj -> Wprojb
// blocks [128,1152): Wsr reorder -> Wkb[co][di*512+dj*256+ci]
// blocks [1152,3712): x fp32 -> xb bf16 (RNE)
__global__ __launch_bounds__(256) void prep_weights(const float* __restrict__ Wq,
                                                    const float* __restrict__ Wkv,
                                                    const float* __restrict__ Wproj,
                                                    const float* __restrict__ Wsr,
                                                    const float* __restrict__ x,
                                                    short* __restrict__ Wqb,
                                                    short* __restrict__ Wkvb,
                                                    short* __restrict__ Wprojb,
                                                    short* __restrict__ Wkb,
                                                    short* __restrict__ xb) {
  int blk = blockIdx.x, tid = threadIdx.x;
  if (blk < 32) {
    cvt8(Wq, Wqb, blk * 256 + tid);
  } else if (blk < 96) {
    cvt8(Wkv, Wkvb, (blk - 32) * 256 + tid);
  } else if (blk < 128) {
    cvt8(Wproj, Wprojb, (blk - 96) * 256 + tid);
  } else if (blk < 1152) {
    int i = (blk - 128) * 256 + tid;
    int co = i >> 10;
    int rem = i & 1023;
    int di = rem >> 9, dj = (rem >> 8) & 1, ci = rem & 255;
    Wkb[i] = f2bf(Wsr[((co * 256 + ci) * 2 + di) * 2 + dj]);
  } else {
    cvt8(x, xb, (blk - 1152) * 256 + tid);
  }
}

// ---------------- 64x64-tile 4-wave MFMA pieces
#define G64_DECL()                                                           \
  __shared__ short As[64][72];                                               \
  __shared__ short Bs[64][72];                                               \
  int tid = threadIdx.x;                                                     \
  int wave = tid >> 6, lg = (tid & 63) >> 4, lr = tid & 15;                  \
  int sr = tid >> 2, sc = tid & 3;                                           \
  floatx4 acc[4] = {{0.f,0.f,0.f,0.f},{0.f,0.f,0.f,0.f},                     \
                    {0.f,0.f,0.f,0.f},{0.f,0.f,0.f,0.f}};

#define G64_MFMA8()                                                          \
    __syncthreads();                                                         \
    {                                                                        \
      bf16x8 af0 = *(bf16x8*)&As[wave * 16 + lr][lg * 8];                    \
      bf16x8 af1 = *(bf16x8*)&As[wave * 16 + lr][32 + lg * 8];               \
      _Pragma("unroll") for (int n = 0; n < 4; ++n) {                        \
        bf16x8 bf0 = *(bf16x8*)&Bs[n * 16 + lr][lg * 8];                     \
        bf16x8 bf1 = *(bf16x8*)&Bs[n * 16 + lr][32 + lg * 8];                \
        acc[n] = __builtin_amdgcn_mfma_f32_16x16x32_bf16(af0, bf0, acc[n], 0, 0, 0); \
        acc[n] = __builtin_amdgcn_mfma_f32_16x16x32_bf16(af1, bf1, acc[n], 0, 0, 0); \
      }                                                                      \
    }

// ---------------- merged q + conv GEMM (one launch, 1600 blocks)
// blocks [0,1280): q GEMM  (A = xb bf16, B = Wqb, K=256) -> qbf, QC folded
// blocks [1280,1600): conv GEMM (A = xb via im2col addressing, B = Wkb,
//                     K=1024) -> cat_pre. SR conv is stride-2 2x2 (disjoint
//                     patches): per 64-aligned k0, (di,dj) is uniform and the
//                     ci range is contiguous in the xb row -> direct bf16x8
//                     loads, no materialized patch buffer.
__global__ __launch_bounds__(256) void gemm_qconv(const short* __restrict__ xb,
                                                  const short* __restrict__ Wqb,
                                                  const short* __restrict__ Wkb,
                                                  short* __restrict__ qbf,
                                                  float* __restrict__ cat_pre) {
  G64_DECL()
  int bidx = blockIdx.x;
  if (bidx < 1280) {
    int bm = (bidx >> 2) * 64, bn = (bidx & 3) * 64;
    for (int k0 = 0; k0 < 256; k0 += 64) {
      bf16x8 a0 = *(const bf16x8*)&xb[(size_t)(bm + sr) * 256 + k0 + sc * 8];
      bf16x8 a1 = *(const bf16x8*)&xb[(size_t)(bm + sr) * 256 + k0 + (sc + 4) * 8];
      bf16x8 b0 = *(const bf16x8*)&Wqb[(size_t)(bn + sr) * 256 + k0 + sc * 8];
      bf16x8 b1 = *(const bf16x8*)&Wqb[(size_t)(bn + sr) * 256 + k0 + (sc + 4) * 8];
      __syncthreads();
      *(bf16x8*)&As[sr][sc * 8] = a0;
      *(bf16x8*)&As[sr][(sc + 4) * 8] = a1;
      *(bf16x8*)&Bs[sr][sc * 8] = b0;
      *(bf16x8*)&Bs[sr][(sc + 4) * 8] = b1;
      G64_MFMA8()
    }
#pragma unroll
    for (int n = 0; n < 4; ++n) {
      int c = bn + 16 * n + lr;
      int h = c >> 5, d = c & 31;
#pragma unroll
      for (int reg = 0; reg < 4; ++reg) {
        int m = bm + wave * 16 + 4 * lg + reg;
        int b = m / NTOK, tok = m - b * NTOK;
        qbf[((size_t)(b * 8 + h) * NTOK + tok) * 32 + d] = f2bf(acc[n][reg] * QC);
      }
    }
  } else {
    int idx = bidx - 1280;
    int mt = idx >> 2;                 // 0..79 m-tile
    int bm = mt * 64, bn = (idx & 3) * 64;
    int bq = mt / 20;                  // batch
    int tloc = (mt % 20) * 64 + sr;    // row within batch's 1280 (cat order)
    for (int k0 = 0; k0 < 1024; k0 += 64) {
      int di = k0 >> 9, dj = (k0 >> 8) & 1;
      int srow;
      if (tloc < 256) {                // z tokens: 16x16 out of 32x32
        int oi = tloc >> 4, oj = tloc & 15;
        srow = bq * NTOK + (2 * oi + di) * 32 + (2 * oj + dj);
      } else {                         // x tokens: 32x32 out of 64x64
        int tt = tloc - 256;
        int oi = tt >> 5, oj = tt & 31;
        srow = bq * NTOK + NZ + (2 * oi + di) * 64 + (2 * oj + dj);
      }
      int cb = k0 & 255;
      bf16x8 a0 = *(const bf16x8*)&xb[(size_t)srow * 256 + cb + sc * 8];
      bf16x8 a1 = *(const bf16x8*)&xb[(size_t)srow * 256 + cb + (sc + 4) * 8];
      bf16x8 b0 = *(const bf16x8*)&Wkb[(size_t)(bn + sr) * 1024 + k0 + sc * 8];
      bf16x8 b1 = *(const bf16x8*)&Wkb[(size_t)(bn + sr) * 1024 + k0 + (sc + 4) * 8];
      __syncthreads();
      *(bf16x8*)&As[sr][sc * 8] = a0;
      *(bf16x8*)&As[sr][(sc + 4) * 8] = a1;
      *(bf16x8*)&Bs[sr][sc * 8] = b0;
      *(bf16x8*)&Bs[sr][(sc + 4) * 8] = b1;
      G64_MFMA8()
    }
#pragma unroll
    for (int n = 0; n < 4; ++n) {
      int c = bn + 16 * n + lr;
#pragma unroll
      for (int reg = 0; reg < 4; ++reg) {
        int m = bm + wave * 16 + 4 * lg + reg;
        cat_pre[(size_t)m * 256 + c] = acc[n][reg];
      }
    }
  }
}

// ---------------- kv GEMM 64-tile: M=5120 N=512 K=256 -> Kbf / Vtb
__global__ __launch_bounds__(256) void gemm_kv64(const short* __restrict__ A,
                                                 const short* __restrict__ Bm,
                                                 short* __restrict__ Kbf,
                                                 short* __restrict__ Vtb) {
  G64_DECL()
  int bm = blockIdx.y * 64, bn = blockIdx.x * 64;
  for (int k0 = 0; k0 < 256; k0 += 64) {
    bf16x8 a0 = *(const bf16x8*)&A[(size_t)(bm + sr) * 256 + k0 + sc * 8];
    bf16x8 a1 = *(const bf16x8*)&A[(size_t)(bm + sr) * 256 + k0 + (sc + 4) * 8];
    bf16x8 b0 = *(const bf16x8*)&Bm[(size_t)(bn + sr) * 256 + k0 + sc * 8];
    bf16x8 b1 = *(const bf16x8*)&Bm[(size_t)(bn + sr) * 256 + k0 + (sc + 4) * 8];
    __syncthreads();
    *(bf16x8*)&As[sr][sc * 8] = a0;
    *(bf16x8*)&As[sr][(sc + 4) * 8] = a1;
    *(bf16x8*)&Bs[sr][sc * 8] = b0;
    *(bf16x8*)&Bs[sr][(sc + 4) * 8] = b1;
    G64_MFMA8()
  }
#pragma unroll
  for (int n = 0; n < 4; ++n) {
    int c = bn + 16 * n + lr;
#pragma unroll
    for (int reg = 0; reg < 4; ++reg) {
      int m = bm + wave * 16 + 4 * lg + reg;
      int b = m / LKV, kvg = m - b * LKV;
      if (c < 256) {
        int h = c >> 5, d = c & 31;
        Kbf[((size_t)(b * 8 + h) * LKV + kvg) * 32 + d] = f2bf(acc[n][reg]);
      } else {
        int cc = c - 256;
        int h = cc >> 5, d = cc & 31;
        int tile = kvg >> 6, kvin = kvg & 63;
        Vtb[(((size_t)(b * 8 + h) * 20 + tile) * 32 + d) * 64 + kvin] = f2bf(acc[n][reg]);
      }
    }
  }
}

// ---------------- proj GEMM 64-tile: A = attn_out bf16, fp32 out + bias
__global__ __launch_bounds__(256) void gemm_proj64(const short* __restrict__ A,
                                                   const short* __restrict__ Bm,
                                                   const float* __restrict__ bias,
                                                   float* __restrict__ Cm) {
  G64_DECL()
  int bm = blockIdx.y * 64, bn = blockIdx.x * 64;
  for (int k0 = 0; k0 < 256; k0 += 64) {
    bf16x8 a0 = *(const bf16x8*)&A[(size_t)(bm + sr) * 256 + k0 + sc * 8];
    bf16x8 a1 = *(const bf16x8*)&A[(size_t)(bm + sr) * 256 + k0 + (sc + 4) * 8];
    bf16x8 b0 = *(const bf16x8*)&Bm[(size_t)(bn + sr) * 256 + k0 + sc * 8];
    bf16x8 b1 = *(const bf16x8*)&Bm[(size_t)(bn + sr) * 256 + k0 + (sc + 4) * 8];
    __syncthreads();
    *(bf16x8*)&As[sr][sc * 8] = a0;
    *(bf16x8*)&As[sr][(sc + 4) * 8] = a1;
    *(bf16x8*)&Bs[sr][sc * 8] = b0;
    *(bf16x8*)&Bs[sr][(sc + 4) * 8] = b1;
    G64_MFMA8()
  }
#pragma unroll
  for (int n = 0; n < 4; ++n) {
    int c = bn + 16 * n + lr;
    float bv = bias[c];
#pragma unroll
    for (int reg = 0; reg < 4; ++reg) {
      int m = bm + wave * 16 + 4 * lg + reg;
      Cm[(size_t)m * 256 + c] = acc[n][reg] + bv;
    }
  }
}

// ---------------- bias + LayerNorm, wave-per-row, bf16 out
__global__ __launch_bounds__(256) void ln_kernel(const float* __restrict__ cat_pre,
                                                 const float* __restrict__ bsr,
                                                 const float* __restrict__ gamma,
                                                 const float* __restrict__ beta,
                                                 short* __restrict__ catb) {
  int row = blockIdx.x * 4 + (threadIdx.x >> 6);
  int lane = threadIdx.x & 63;
  float4 v = *(const float4*)&cat_pre[(size_t)row * 256 + lane * 4];
  float4 bb = *(const float4*)&bsr[lane * 4];
  v.x += bb.x; v.y += bb.y; v.z += bb.z; v.w += bb.w;
  float s = (v.x + v.y) + (v.z + v.w);
#pragma unroll
  for (int mask = 1; mask < 64; mask <<= 1) s += __shfl_xor(s, mask, 64);
  float mu = s * (1.f / 256.f);
  float4 dv;
  dv.x = v.x - mu; dv.y = v.y - mu; dv.z = v.z - mu; dv.w = v.w - mu;
  float q = dv.x * dv.x + dv.y * dv.y + dv.z * dv.z + dv.w * dv.w;
#pragma unroll
  for (int mask = 1; mask < 64; mask <<= 1) q += __shfl_xor(q, mask, 64);
  float rs = rsqrtf(q * (1.f / 256.f) + 1e-5f);
  float4 g = *(const float4*)&gamma[lane * 4];
  float4 be = *(const float4*)&beta[lane * 4];
  uint2 st;
  st.x = pk2(dv.x * rs * g.x + be.x, dv.y * rs * g.y + be.y);
  st.y = pk2(dv.z * rs * g.z + be.z, dv.w * rs * g.w + be.w);
  *(uint2*)&catb[(size_t)row * 256 + lane * 4] = st;
}

// ---------------- fused MFMA flash attention: 64 q rows/wave, 4-wave blocks.
// logical blocks [0,512): x-part (bh = blk>>4, q0 = NZ + (blk&15)*256, kv 1280)
// logical blocks [512,640): z-part (bh = idx>>2, q0 = (idx&3)*256, kv 256)
// XCD chunked swizzle (640 = 8*80): the 16 x-blocks sharing one head's K/V
// land on one XCD's L2. setprio(1) wraps the MFMA clusters (T5).
// sched_barrier pins preserve the verified Ps write->read program order.
__global__ __launch_bounds__(256) void attn_fused(const short* __restrict__ qbf,
                                                  const short* __restrict__ Kbf,
                                                  const short* __restrict__ Vtb,
                                                  short* __restrict__ attn_out) {
  int orig = blockIdx.x;
  int blk = (orig & 7) * 80 + (orig >> 3);   // bijective, 5 heads/XCD chunk
  int bh, q0, kvlen;
  if (blk < 512) {
    bh = blk >> 4; q0 = NZ + (blk & 15) * 256; kvlen = LKV;
  } else {
    int idx = blk - 512;
    bh = idx >> 2; q0 = (idx & 3) * 256; kvlen = 256;
  }
  int b = bh >> 3, hh = bh & 7;
  int tid = threadIdx.x;
  int wave = tid >> 6, lane = tid & 63, lg = lane >> 4, lr = lane & 15;

  __shared__ short Ps[4][64][72];   // per-wave P[q][kv]; row 144B

  int qtok = q0 + wave * 64;
  const short* qb = qbf + ((size_t)bh * NTOK + qtok) * 32;
  bf16x8 qf[4];
#pragma unroll
  for (int qi = 0; qi < 4; ++qi)
    qf[qi] = *(const bf16x8*)&qb[(16 * qi + lr) * 32 + lg * 8];

  const short* Kb = Kbf + (size_t)bh * LKV * 32;
  const short* Vb = Vtb + (size_t)bh * 20 * 2048;

  floatx4 oacc[4][2];
#pragma unroll
  for (int qi = 0; qi < 4; ++qi)
#pragma unroll
    for (int n = 0; n < 2; ++n) oacc[qi][n] = (floatx4){0.f, 0.f, 0.f, 0.f};
  float lsum[4] = {0.f, 0.f, 0.f, 0.f};

  bf16x8 kfc[4], vfc[2][2];
#pragma unroll
  for (int m = 0; m < 4; ++m)
    kfc[m] = *(const bf16x8*)&Kb[(size_t)(16 * m + lr) * 32 + lg * 8];
#pragma unroll
  for (int n = 0; n < 2; ++n)
#pragma unroll
    for (int kb = 0; kb < 2; ++kb)
      vfc[n][kb] = *(const bf16x8*)&Vb[(16 * n + lr) * 64 + kb * 32 + lg * 8];

  for (int l0 = 0; l0 < kvlen; l0 += 64) {
    // pin: previous iteration's Ps reads stay before this iteration's stores
    __builtin_amdgcn_sched_barrier(0);
#pragma unroll
    for (int qi = 0; qi < 4; ++qi) {
      floatx4 st[4];
      __builtin_amdgcn_s_setprio(1);
#pragma unroll
      for (int m = 0; m < 4; ++m)
        st[m] = __builtin_amdgcn_mfma_f32_16x16x32_bf16(
            kfc[m], qf[qi], (floatx4){0.f, 0.f, 0.f, 0.f}, 0, 0, 0);
      __builtin_amdgcn_s_setprio(0);
      int pr = 16 * qi + lr;
#pragma unroll
      for (int m = 0; m < 4; ++m) {
        float p0 = __builtin_amdgcn_exp2f(st[m][0]);
        float p1 = __builtin_amdgcn_exp2f(st[m][1]);
        float p2 = __builtin_amdgcn_exp2f(st[m][2]);
        float p3 = __builtin_amdgcn_exp2f(st[m][3]);
        lsum[qi] += (p0 + p1) + (p2 + p3);
        uint2 w;
        w.x = pk2f(p0, p1);
        w.y = pk2f(p2, p3);
        *(uint2*)&Ps[wave][pr][16 * m + 4 * lg] = w;
      }
    }

    // prefetch next tile's fragments
    bf16x8 kfn[4], vfn[2][2];
    int l1 = l0 + 64;
    if (l1 < kvlen) {
      const short* Vbt = Vb + (l1 >> 6) * 2048;
#pragma unroll
      for (int m = 0; m < 4; ++m)
        kfn[m] = *(const bf16x8*)&Kb[(size_t)(l1 + 16 * m + lr) * 32 + lg * 8];
#pragma unroll
      for (int n = 0; n < 2; ++n)
#pragma unroll
        for (int kb = 0; kb < 2; ++kb)
          vfn[n][kb] = *(const bf16x8*)&Vbt[(16 * n + lr) * 64 + kb * 32 + lg * 8];
    }

    // pin: all Ps stores (above) complete in program order before PV reads
    __builtin_amdgcn_sched_barrier(0);

    // PV
    __builtin_amdgcn_s_setprio(1);
#pragma unroll
    for (int qi = 0; qi < 4; ++qi)
#pragma unroll
      for (int kb = 0; kb < 2; ++kb) {
        bf16x8 pf = *(bf16x8*)&Ps[wave][16 * qi + lr][kb * 32 + lg * 8];
#pragma unroll
        for (int n = 0; n < 2; ++n)
          oacc[qi][n] = __builtin_amdgcn_mfma_f32_16x16x32_bf16(pf, vfc[n][kb], oacc[qi][n], 0, 0, 0);
      }
    __builtin_amdgcn_s_setprio(0);

#pragma unroll
    for (int m = 0; m < 4; ++m) kfc[m] = kfn[m];
#pragma unroll
    for (int n = 0; n < 2; ++n)
#pragma unroll
      for (int kb = 0; kb < 2; ++kb) vfc[n][kb] = vfn[n][kb];
  }

#pragma unroll
  for (int qi = 0; qi < 4; ++qi) {
    lsum[qi] += __shfl_xor(lsum[qi], 16, 64);
    lsum[qi] += __shfl_xor(lsum[qi], 32, 64);
  }

#pragma unroll
  for (int qi = 0; qi < 4; ++qi)
#pragma unroll
    for (int reg = 0; reg < 4; ++reg) {
      float lv = __shfl(lsum[qi], 4 * lg + reg, 64);
      float inv = 1.f / lv;
      int gr = b * NTOK + qtok + 16 * qi + 4 * lg + reg;
      short* ob = attn_out + (size_t)gr * CCH + hh * DHEAD;
      ob[lr]      = f2bf(oacc[qi][0][reg] * inv);
      ob[16 + lr] = f2bf(oacc[qi][1][reg] * inv);
    }
}

extern "C" void kernel_launch(void* const* d_in, const int* in_sizes, int n_in,
                              void* d_out, int out_size, void* d_ws, size_t ws_size,
                              hipStream_t stream) {
  (void)in_sizes; (void)n_in; (void)out_size; (void)ws_size;
  const float* x     = (const float*)d_in[0];
  const float* Wq    = (const float*)d_in[1];
  const float* Wkv   = (const float*)d_in[2];
  const float* Wsr   = (const float*)d_in[3];
  const float* bsr   = (const float*)d_in[4];
  const float* gamma = (const float*)d_in[5];
  const float* beta  = (const float*)d_in[6];
  const float* Wproj = (const float*)d_in[7];
  const float* bproj = (const float*)d_in[8];
  float* out = (float*)d_out;
  float* ws  = (float*)d_ws;

  // workspace (float offsets), all disjoint (~45 MB):
  short* qbf      = (short*)ws;                   // [0, 2,621,440)
  short* attn_out = (short*)(ws + 2621440);       // [2,621,440, 5,242,880)
  float* cat_pre  = ws + 7864320;                 // [7,864,320, 9,175,040)
  short* catb     = (short*)(ws + 9175040);       // [9,175,040, 9,830,400)
  short* Kbf      = (short*)(ws + 9830400);       // [9,830,400, 10,485,760)
  short* Vtb      = (short*)(ws + 10485760);      // [10,485,760, 11,141,120)
  short* Wqb      = (short*)(ws + 11141120);      // +32,768 sh
  short* Wkvb     = (short*)(ws + 11173888);      // +65,536 sh
  short* Wkb      = (short*)(ws + 11239424);      // +131,072 sh
  short* Wprojb   = (short*)(ws + 11370496);      // +32,768 sh -> ends 11,403,264 f
  // xb (bf16 x, 5,242,880 sh) time-shares the attn_out region: xb is live
  // prep->gemm_qconv; attn_out is written only later (same stream, ordered).
  short* xb       = attn_out;

  prep_weights<<<3712, 256, 0, stream>>>(Wq, Wkv, Wproj, Wsr, x, Wqb, Wkvb, Wprojb, Wkb, xb);
  // q (blocks 0..1279, A=xb bf16) + conv (1280..1599, A=xb direct im2col addressing)
  gemm_qconv<<<1600, 256, 0, stream>>>(xb, Wqb, Wkb, qbf, cat_pre);
  ln_kernel<<<1280, 256, 0, stream>>>(cat_pre, bsr, gamma, beta, catb);
  // kv = cat @ Wkv^T (5120 x 512, K=256), 640 blocks
  gemm_kv64<<<dim3(8, 80), 256, 0, stream>>>(catb, Wkvb, Kbf, Vtb);
  // fused attention: 512 x-blocks + 128 z-blocks, 256 thr, 64 q/wave
  attn_fused<<<640, 256, 0, stream>>>(qbf, Kbf, Vtb, attn_out);
  // out = attn_out @ Wproj^T + bproj, 1280 blocks
  gemm_proj64<<<dim3(4, 320), 256, 0, stream>>>(attn_out, Wprojb, bproj, out);
}

// Round 7
// 183.579 us; speedup vs baseline: 1.1470x; 1.1470x over previous
//
#include <hip/hip_runtime.h>
#include <hip/hip_bf16.h>
#include <cstddef>

#define BATCH 4
#define CCH 256
#define NHEAD 8
#define DHEAD 32
#define NZ 1024
#define NX 4096
#define NTOK 5120
#define LKV 1280
#define QC 0.25503486f   // SCALE * log2(e), folded into q

typedef __attribute__((ext_vector_type(8))) short bf16x8;
typedef __attribute__((ext_vector_type(4))) float floatx4;

__device__ inline short f2bf(float f) {
  __hip_bfloat16 h = __float2bfloat16(f);
  return __builtin_bit_cast(short, h);
}
__device__ inline unsigned int pk2(float a, float b) {   // RNE
  unsigned int lo = (unsigned short)f2bf(a);
  unsigned int hi = (unsigned short)f2bf(b);
  return lo | (hi << 16);
}
// fast pack: round-half-up + byte-perm (hot path; a,b > 0)
__device__ inline unsigned int pk2f(float a, float b) {
  unsigned int ua = __builtin_bit_cast(unsigned int, a) + 0x8000u;
  unsigned int ub = __builtin_bit_cast(unsigned int, b) + 0x8000u;
  return __builtin_amdgcn_perm(ub, ua, 0x07060302u);
}
__device__ inline void cvt8(const float* __restrict__ src, short* __restrict__ dst, int i) {
  float4 v0 = ((const float4*)src)[i * 2];
  float4 v1 = ((const float4*)src)[i * 2 + 1];
  uint4 u;
  u.x = pk2(v0.x, v0.y); u.y = pk2(v0.z, v0.w);
  u.z = pk2(v1.x, v1.y); u.w = pk2(v1.z, v1.w);
  ((uint4*)dst)[i] = u;
}

// ---------------- prep: weight converts + Wsr reorder + x->bf16, one launch
// blocks [0,32): Wq -> Wqb ; [32,96): Wkv -> Wkvb ; [96,128): Wproj -> Wprojb
// blocks [128,1152): Wsr reorder -> Wkb[co][di*512+dj*256+ci]
// blocks [1152,3712): x fp32 -> xb bf16 (RNE)
__global__ __launch_bounds__(256) void prep_weights(const float* __restrict__ Wq,
                                                    const float* __restrict__ Wkv,
                                                    const float* __restrict__ Wproj,
                                                    const float* __restrict__ Wsr,
                                                    const float* __restrict__ x,
                                                    short* __restrict__ Wqb,
                                                    short* __restrict__ Wkvb,
                                                    short* __restrict__ Wprojb,
                                                    short* __restrict__ Wkb,
                                                    short* __restrict__ xb) {
  int blk = blockIdx.x, tid = threadIdx.x;
  if (blk < 32) {
    cvt8(Wq, Wqb, blk * 256 + tid);
  } else if (blk < 96) {
    cvt8(Wkv, Wkvb, (blk - 32) * 256 + tid);
  } else if (blk < 128) {
    cvt8(Wproj, Wprojb, (blk - 96) * 256 + tid);
  } else if (blk < 1152) {
    int i = (blk - 128) * 256 + tid;
    int co = i >> 10;
    int rem = i & 1023;
    int di = rem >> 9, dj = (rem >> 8) & 1, ci = rem & 255;
    Wkb[i] = f2bf(Wsr[((co * 256 + ci) * 2 + di) * 2 + dj]);
  } else {
    cvt8(x, xb, (blk - 1152) * 256 + tid);
  }
}

// ---------------- 64x64-tile 4-wave MFMA pieces
#define G64_DECL()                                                           \
  __shared__ short As[64][72];                                               \
  __shared__ short Bs[64][72];                                               \
  int tid = threadIdx.x;                                                     \
  int wave = tid >> 6, lg = (tid & 63) >> 4, lr = tid & 15;                  \
  int sr = tid >> 2, sc = tid & 3;                                           \
  floatx4 acc[4] = {{0.f,0.f,0.f,0.f},{0.f,0.f,0.f,0.f},                     \
                    {0.f,0.f,0.f,0.f},{0.f,0.f,0.f,0.f}};

#define G64_MFMA8()                                                          \
    __syncthreads();                                                         \
    {                                                                        \
      bf16x8 af0 = *(bf16x8*)&As[wave * 16 + lr][lg * 8];                    \
      bf16x8 af1 = *(bf16x8*)&As[wave * 16 + lr][32 + lg * 8];               \
      _Pragma("unroll") for (int n = 0; n < 4; ++n) {                        \
        bf16x8 bf0 = *(bf16x8*)&Bs[n * 16 + lr][lg * 8];                     \
        bf16x8 bf1 = *(bf16x8*)&Bs[n * 16 + lr][32 + lg * 8];                \
        acc[n] = __builtin_amdgcn_mfma_f32_16x16x32_bf16(af0, bf0, acc[n], 0, 0, 0); \
        acc[n] = __builtin_amdgcn_mfma_f32_16x16x32_bf16(af1, bf1, acc[n], 0, 0, 0); \
      }                                                                      \
    }

// ---------------- merged q + conv GEMM (one launch, 1600 blocks)
// blocks [0,1280): q GEMM  (A = xb bf16, B = Wqb, K=256) -> qbf, QC folded
// blocks [1280,1600): conv GEMM (A = xb via im2col addressing, B = Wkb,
//                     K=1024) -> cat_pre. SR conv is stride-2 2x2 (disjoint
//                     patches): per 64-aligned k0, (di,dj) is uniform and the
//                     ci range is contiguous in the xb row -> direct bf16x8
//                     loads, no materialized patch buffer.
__global__ __launch_bounds__(256) void gemm_qconv(const short* __restrict__ xb,
                                                  const short* __restrict__ Wqb,
                                                  const short* __restrict__ Wkb,
                                                  short* __restrict__ qbf,
                                                  float* __restrict__ cat_pre) {
  G64_DECL()
  int bidx = blockIdx.x;
  if (bidx < 1280) {
    int bm = (bidx >> 2) * 64, bn = (bidx & 3) * 64;
    for (int k0 = 0; k0 < 256; k0 += 64) {
      bf16x8 a0 = *(const bf16x8*)&xb[(size_t)(bm + sr) * 256 + k0 + sc * 8];
      bf16x8 a1 = *(const bf16x8*)&xb[(size_t)(bm + sr) * 256 + k0 + (sc + 4) * 8];
      bf16x8 b0 = *(const bf16x8*)&Wqb[(size_t)(bn + sr) * 256 + k0 + sc * 8];
      bf16x8 b1 = *(const bf16x8*)&Wqb[(size_t)(bn + sr) * 256 + k0 + (sc + 4) * 8];
      __syncthreads();
      *(bf16x8*)&As[sr][sc * 8] = a0;
      *(bf16x8*)&As[sr][(sc + 4) * 8] = a1;
      *(bf16x8*)&Bs[sr][sc * 8] = b0;
      *(bf16x8*)&Bs[sr][(sc + 4) * 8] = b1;
      G64_MFMA8()
    }
#pragma unroll
    for (int n = 0; n < 4; ++n) {
      int c = bn + 16 * n + lr;
      int h = c >> 5, d = c & 31;
#pragma unroll
      for (int reg = 0; reg < 4; ++reg) {
        int m = bm + wave * 16 + 4 * lg + reg;
        int b = m / NTOK, tok = m - b * NTOK;
        qbf[((size_t)(b * 8 + h) * NTOK + tok) * 32 + d] = f2bf(acc[n][reg] * QC);
      }
    }
  } else {
    int idx = bidx - 1280;
    int mt = idx >> 2;                 // 0..79 m-tile
    int bm = mt * 64, bn = (idx & 3) * 64;
    int bq = mt / 20;                  // batch
    int tloc = (mt % 20) * 64 + sr;    // row within batch's 1280 (cat order)
    for (int k0 = 0; k0 < 1024; k0 += 64) {
      int di = k0 >> 9, dj = (k0 >> 8) & 1;
      int srow;
      if (tloc < 256) {                // z tokens: 16x16 out of 32x32
        int oi = tloc >> 4, oj = tloc & 15;
        srow = bq * NTOK + (2 * oi + di) * 32 + (2 * oj + dj);
      } else {                         // x tokens: 32x32 out of 64x64
        int tt = tloc - 256;
        int oi = tt >> 5, oj = tt & 31;
        srow = bq * NTOK + NZ + (2 * oi + di) * 64 + (2 * oj + dj);
      }
      int cb = k0 & 255;
      bf16x8 a0 = *(const bf16x8*)&xb[(size_t)srow * 256 + cb + sc * 8];
      bf16x8 a1 = *(const bf16x8*)&xb[(size_t)srow * 256 + cb + (sc + 4) * 8];
      bf16x8 b0 = *(const bf16x8*)&Wkb[(size_t)(bn + sr) * 1024 + k0 + sc * 8];
      bf16x8 b1 = *(const bf16x8*)&Wkb[(size_t)(bn + sr) * 1024 + k0 + (sc + 4) * 8];
      __syncthreads();
      *(bf16x8*)&As[sr][sc * 8] = a0;
      *(bf16x8*)&As[sr][(sc + 4) * 8] = a1;
      *(bf16x8*)&Bs[sr][sc * 8] = b0;
      *(bf16x8*)&Bs[sr][(sc + 4) * 8] = b1;
      G64_MFMA8()
    }
#pragma unroll
    for (int n = 0; n < 4; ++n) {
      int c = bn + 16 * n + lr;
#pragma unroll
      for (int reg = 0; reg < 4; ++reg) {
        int m = bm + wave * 16 + 4 * lg + reg;
        cat_pre[(size_t)m * 256 + c] = acc[n][reg];
      }
    }
  }
}

// ---------------- kv GEMM 64-tile: M=5120 N=512 K=256 -> Kbf / Vtb
__global__ __launch_bounds__(256) void gemm_kv64(const short* __restrict__ A,
                                                 const short* __restrict__ Bm,
                                                 short* __restrict__ Kbf,
                                                 short* __restrict__ Vtb) {
  G64_DECL()
  int bm = blockIdx.y * 64, bn = blockIdx.x * 64;
  for (int k0 = 0; k0 < 256; k0 += 64) {
    bf16x8 a0 = *(const bf16x8*)&A[(size_t)(bm + sr) * 256 + k0 + sc * 8];
    bf16x8 a1 = *(const bf16x8*)&A[(size_t)(bm + sr) * 256 + k0 + (sc + 4) * 8];
    bf16x8 b0 = *(const bf16x8*)&Bm[(size_t)(bn + sr) * 256 + k0 + sc * 8];
    bf16x8 b1 = *(const bf16x8*)&Bm[(size_t)(bn + sr) * 256 + k0 + (sc + 4) * 8];
    __syncthreads();
    *(bf16x8*)&As[sr][sc * 8] = a0;
    *(bf16x8*)&As[sr][(sc + 4) * 8] = a1;
    *(bf16x8*)&Bs[sr][sc * 8] = b0;
    *(bf16x8*)&Bs[sr][(sc + 4) * 8] = b1;
    G64_MFMA8()
  }
#pragma unroll
  for (int n = 0; n < 4; ++n) {
    int c = bn + 16 * n + lr;
#pragma unroll
    for (int reg = 0; reg < 4; ++reg) {
      int m = bm + wave * 16 + 4 * lg + reg;
      int b = m / LKV, kvg = m - b * LKV;
      if (c < 256) {
        int h = c >> 5, d = c & 31;
        Kbf[((size_t)(b * 8 + h) * LKV + kvg) * 32 + d] = f2bf(acc[n][reg]);
      } else {
        int cc = c - 256;
        int h = cc >> 5, d = cc & 31;
        int tile = kvg >> 6, kvin = kvg & 63;
        Vtb[(((size_t)(b * 8 + h) * 20 + tile) * 32 + d) * 64 + kvin] = f2bf(acc[n][reg]);
      }
    }
  }
}

// ---------------- proj GEMM 64-tile: A = attn_out bf16, fp32 out + bias
__global__ __launch_bounds__(256) void gemm_proj64(const short* __restrict__ A,
                                                   const short* __restrict__ Bm,
                                                   const float* __restrict__ bias,
                                                   float* __restrict__ Cm) {
  G64_DECL()
  int bm = blockIdx.y * 64, bn = blockIdx.x * 64;
  for (int k0 = 0; k0 < 256; k0 += 64) {
    bf16x8 a0 = *(const bf16x8*)&A[(size_t)(bm + sr) * 256 + k0 + sc * 8];
    bf16x8 a1 = *(const bf16x8*)&A[(size_t)(bm + sr) * 256 + k0 + (sc + 4) * 8];
    bf16x8 b0 = *(const bf16x8*)&Bm[(size_t)(bn + sr) * 256 + k0 + sc * 8];
    bf16x8 b1 = *(const bf16x8*)&Bm[(size_t)(bn + sr) * 256 + k0 + (sc + 4) * 8];
    __syncthreads();
    *(bf16x8*)&As[sr][sc * 8] = a0;
    *(bf16x8*)&As[sr][(sc + 4) * 8] = a1;
    *(bf16x8*)&Bs[sr][sc * 8] = b0;
    *(bf16x8*)&Bs[sr][(sc + 4) * 8] = b1;
    G64_MFMA8()
  }
#pragma unroll
  for (int n = 0; n < 4; ++n) {
    int c = bn + 16 * n + lr;
    float bv = bias[c];
#pragma unroll
    for (int reg = 0; reg < 4; ++reg) {
      int m = bm + wave * 16 + 4 * lg + reg;
      Cm[(size_t)m * 256 + c] = acc[n][reg] + bv;
    }
  }
}

// ---------------- bias + LayerNorm, wave-per-row, bf16 out
__global__ __launch_bounds__(256) void ln_kernel(const float* __restrict__ cat_pre,
                                                 const float* __restrict__ bsr,
                                                 const float* __restrict__ gamma,
                                                 const float* __restrict__ beta,
                                                 short* __restrict__ catb) {
  int row = blockIdx.x * 4 + (threadIdx.x >> 6);
  int lane = threadIdx.x & 63;
  float4 v = *(const float4*)&cat_pre[(size_t)row * 256 + lane * 4];
  float4 bb = *(const float4*)&bsr[lane * 4];
  v.x += bb.x; v.y += bb.y; v.z += bb.z; v.w += bb.w;
  float s = (v.x + v.y) + (v.z + v.w);
#pragma unroll
  for (int mask = 1; mask < 64; mask <<= 1) s += __shfl_xor(s, mask, 64);
  float mu = s * (1.f / 256.f);
  float4 dv;
  dv.x = v.x - mu; dv.y = v.y - mu; dv.z = v.z - mu; dv.w = v.w - mu;
  float q = dv.x * dv.x + dv.y * dv.y + dv.z * dv.z + dv.w * dv.w;
#pragma unroll
  for (int mask = 1; mask < 64; mask <<= 1) q += __shfl_xor(q, mask, 64);
  float rs = rsqrtf(q * (1.f / 256.f) + 1e-5f);
  float4 g = *(const float4*)&gamma[lane * 4];
  float4 be = *(const float4*)&beta[lane * 4];
  uint2 st;
  st.x = pk2(dv.x * rs * g.x + be.x, dv.y * rs * g.y + be.y);
  st.y = pk2(dv.z * rs * g.z + be.z, dv.w * rs * g.w + be.w);
  *(uint2*)&catb[(size_t)row * 256 + lane * 4] = st;
}

// ---------------- fused MFMA flash attention: 64 q rows/wave, 4-wave blocks.
// logical blocks [0,512): x-part (bh = blk>>4, q0 = NZ + (blk&15)*256, kv 1280)
// logical blocks [512,640): z-part (bh = idx>>2, q0 = (idx&3)*256, kv 256)
// Balanced head-affinity swizzle: orig = s*8 + xcd; XCD 'xcd' serves heads
// {xcd, xcd+8, xcd+16, xcd+24}: exactly 64 long + 16 short blocks per residue
// class (preserves round-5's load balance) while confining each XCD's K/V
// working set to 4 heads (640 KB, L2-resident). Round-6's chunked swizzle got
// the locality (FETCH 27.6->8.2 MB) but broke balance (76us); this keeps both.
// sched_barrier pins preserve the verified Ps write->read program order.
__global__ __launch_bounds__(256) void attn_fused(const short* __restrict__ qbf,
                                                  const short* __restrict__ Kbf,
                                                  const short* __restrict__ Vtb,
                                                  short* __restrict__ attn_out) {
  int orig = blockIdx.x;
  int xcd = orig & 7, s = orig >> 3;   // s in [0,80)
  int blk;
  if (s < 64) {
    int bhh = xcd + 8 * (s >> 4);      // head group
    blk = bhh * 16 + (s & 15);         // x-part logical [0,512)
  } else {
    int s2 = s - 64;
    int bhh = xcd + 8 * (s2 >> 2);
    blk = 512 + bhh * 4 + (s2 & 3);    // z-part logical [512,640)
  }
  int bh, q0, kvlen;
  if (blk < 512) {
    bh = blk >> 4; q0 = NZ + (blk & 15) * 256; kvlen = LKV;
  } else {
    int idx = blk - 512;
    bh = idx >> 2; q0 = (idx & 3) * 256; kvlen = 256;
  }
  int b = bh >> 3, hh = bh & 7;
  int tid = threadIdx.x;
  int wave = tid >> 6, lane = tid & 63, lg = lane >> 4, lr = lane & 15;

  __shared__ short Ps[4][64][72];   // per-wave P[q][kv]; row 144B

  int qtok = q0 + wave * 64;
  const short* qb = qbf + ((size_t)bh * NTOK + qtok) * 32;
  bf16x8 qf[4];
#pragma unroll
  for (int qi = 0; qi < 4; ++qi)
    qf[qi] = *(const bf16x8*)&qb[(16 * qi + lr) * 32 + lg * 8];

  const short* Kb = Kbf + (size_t)bh * LKV * 32;
  const short* Vb = Vtb + (size_t)bh * 20 * 2048;

  floatx4 oacc[4][2];
#pragma unroll
  for (int qi = 0; qi < 4; ++qi)
#pragma unroll
    for (int n = 0; n < 2; ++n) oacc[qi][n] = (floatx4){0.f, 0.f, 0.f, 0.f};
  float lsum[4] = {0.f, 0.f, 0.f, 0.f};

  bf16x8 kfc[4], vfc[2][2];
#pragma unroll
  for (int m = 0; m < 4; ++m)
    kfc[m] = *(const bf16x8*)&Kb[(size_t)(16 * m + lr) * 32 + lg * 8];
#pragma unroll
  for (int n = 0; n < 2; ++n)
#pragma unroll
    for (int kb = 0; kb < 2; ++kb)
      vfc[n][kb] = *(const bf16x8*)&Vb[(16 * n + lr) * 64 + kb * 32 + lg * 8];

  for (int l0 = 0; l0 < kvlen; l0 += 64) {
    // pin: previous iteration's Ps reads stay before this iteration's stores
    __builtin_amdgcn_sched_barrier(0);
#pragma unroll
    for (int qi = 0; qi < 4; ++qi) {
      floatx4 st[4];
#pragma unroll
      for (int m = 0; m < 4; ++m)
        st[m] = __builtin_amdgcn_mfma_f32_16x16x32_bf16(
            kfc[m], qf[qi], (floatx4){0.f, 0.f, 0.f, 0.f}, 0, 0, 0);
      int pr = 16 * qi + lr;
#pragma unroll
      for (int m = 0; m < 4; ++m) {
        float p0 = __builtin_amdgcn_exp2f(st[m][0]);
        float p1 = __builtin_amdgcn_exp2f(st[m][1]);
        float p2 = __builtin_amdgcn_exp2f(st[m][2]);
        float p3 = __builtin_amdgcn_exp2f(st[m][3]);
        lsum[qi] += (p0 + p1) + (p2 + p3);
        uint2 w;
        w.x = pk2f(p0, p1);
        w.y = pk2f(p2, p3);
        *(uint2*)&Ps[wave][pr][16 * m + 4 * lg] = w;
      }
    }

    // prefetch next tile's fragments
    bf16x8 kfn[4], vfn[2][2];
    int l1 = l0 + 64;
    if (l1 < kvlen) {
      const short* Vbt = Vb + (l1 >> 6) * 2048;
#pragma unroll
      for (int m = 0; m < 4; ++m)
        kfn[m] = *(const bf16x8*)&Kb[(size_t)(l1 + 16 * m + lr) * 32 + lg * 8];
#pragma unroll
      for (int n = 0; n < 2; ++n)
#pragma unroll
        for (int kb = 0; kb < 2; ++kb)
          vfn[n][kb] = *(const bf16x8*)&Vbt[(16 * n + lr) * 64 + kb * 32 + lg * 8];
    }

    // pin: all Ps stores (above) complete in program order before PV reads
    __builtin_amdgcn_sched_barrier(0);

    // PV
#pragma unroll
    for (int qi = 0; qi < 4; ++qi)
#pragma unroll
      for (int kb = 0; kb < 2; ++kb) {
        bf16x8 pf = *(bf16x8*)&Ps[wave][16 * qi + lr][kb * 32 + lg * 8];
#pragma unroll
        for (int n = 0; n < 2; ++n)
          oacc[qi][n] = __builtin_amdgcn_mfma_f32_16x16x32_bf16(pf, vfc[n][kb], oacc[qi][n], 0, 0, 0);
      }

#pragma unroll
    for (int m = 0; m < 4; ++m) kfc[m] = kfn[m];
#pragma unroll
    for (int n = 0; n < 2; ++n)
#pragma unroll
      for (int kb = 0; kb < 2; ++kb) vfc[n][kb] = vfn[n][kb];
  }

#pragma unroll
  for (int qi = 0; qi < 4; ++qi) {
    lsum[qi] += __shfl_xor(lsum[qi], 16, 64);
    lsum[qi] += __shfl_xor(lsum[qi], 32, 64);
  }

#pragma unroll
  for (int qi = 0; qi < 4; ++qi)
#pragma unroll
    for (int reg = 0; reg < 4; ++reg) {
      float lv = __shfl(lsum[qi], 4 * lg + reg, 64);
      float inv = 1.f / lv;
      int gr = b * NTOK + qtok + 16 * qi + 4 * lg + reg;
      short* ob = attn_out + (size_t)gr * CCH + hh * DHEAD;
      ob[lr]      = f2bf(oacc[qi][0][reg] * inv);
      ob[16 + lr] = f2bf(oacc[qi][1][reg] * inv);
    }
}

extern "C" void kernel_launch(void* const* d_in, const int* in_sizes, int n_in,
                              void* d_out, int out_size, void* d_ws, size_t ws_size,
                              hipStream_t stream) {
  (void)in_sizes; (void)n_in; (void)out_size; (void)ws_size;
  const float* x     = (const float*)d_in[0];
  const float* Wq    = (const float*)d_in[1];
  const float* Wkv   = (const float*)d_in[2];
  const float* Wsr   = (const float*)d_in[3];
  const float* bsr   = (const float*)d_in[4];
  const float* gamma = (const float*)d_in[5];
  const float* beta  = (const float*)d_in[6];
  const float* Wproj = (const float*)d_in[7];
  const float* bproj = (const float*)d_in[8];
  float* out = (float*)d_out;
  float* ws  = (float*)d_ws;

  // workspace (float offsets), all disjoint (~45 MB):
  short* qbf      = (short*)ws;                   // [0, 2,621,440)
  short* attn_out = (short*)(ws + 2621440);       // [2,621,440, 5,242,880)
  float* cat_pre  = ws + 7864320;                 // [7,864,320, 9,175,040)
  short* catb     = (short*)(ws + 9175040);       // [9,175,040, 9,830,400)
  short* Kbf      = (short*)(ws + 9830400);       // [9,830,400, 10,485,760)
  short* Vtb      = (short*)(ws + 10485760);      // [10,485,760, 11,141,120)
  short* Wqb      = (short*)(ws + 11141120);      // +32,768 sh
  short* Wkvb     = (short*)(ws + 11173888);      // +65,536 sh
  short* Wkb      = (short*)(ws + 11239424);      // +131,072 sh
  short* Wprojb   = (short*)(ws + 11370496);      // +32,768 sh -> ends 11,403,264 f
  // xb (bf16 x, 5,242,880 sh) time-shares the attn_out region: xb is live
  // prep->gemm_qconv; attn_out is written only later (same stream, ordered).
  short* xb       = attn_out;

  prep_weights<<<3712, 256, 0, stream>>>(Wq, Wkv, Wproj, Wsr, x, Wqb, Wkvb, Wprojb, Wkb, xb);
  // q (blocks 0..1279, A=xb bf16) + conv (1280..1599, A=xb direct im2col addressing)
  gemm_qconv<<<1600, 256, 0, stream>>>(xb, Wqb, Wkb, qbf, cat_pre);
  ln_kernel<<<1280, 256, 0, stream>>>(cat_pre, bsr, gamma, beta, catb);
  // kv = cat @ Wkv^T (5120 x 512, K=256), 640 blocks
  gemm_kv64<<<dim3(8, 80), 256, 0, stream>>>(catb, Wkvb, Kbf, Vtb);
  // fused attention: 512 x-blocks + 128 z-blocks, 256 thr, 64 q/wave
  attn_fused<<<640, 256, 0, stream>>>(qbf, Kbf, Vtb, attn_out);
  // out = attn_out @ Wproj^T + bproj, 1280 blocks
  gemm_proj64<<<dim3(4, 320), 256, 0, stream>>>(attn_out, Wprojb, bproj, out);
}